// Round 4
// baseline (442.290 us; speedup 1.0000x reference)
//
#include <hip/hip_runtime.h>

// Problem constants: B=4, S=2048, D=1024, H=16, DK=64
#define BB 4
#define SS 2048
#define DD 1024
#define HH 16
#define DKK 64
#define MTOT (BB * SS)          // 8192
#define QKV_N (MTOT * DD)       // 8388608
#define W_N (DD * DD)           // 1048576

typedef __attribute__((ext_vector_type(8))) short short8;     // 8 bf16 (MFMA A/B frag)
typedef __attribute__((ext_vector_type(4))) float f32x4;      // MFMA C/D frag
typedef __attribute__((ext_vector_type(4))) unsigned short u16x4;
typedef unsigned short ushort_t;

#define GP(p) ((__attribute__((address_space(1))) void*)(p))
#define LP(p) ((__attribute__((address_space(3))) void*)(p))

// exp2-domain softmax: Q pre-scaled by log2(e)/8 so p = 2^(s-m) via v_exp_f32
#if __has_builtin(__builtin_amdgcn_exp2f)
#define EXP2(x) __builtin_amdgcn_exp2f(x)
#else
#define EXP2(x) __expf((x) * 0.6931471805599453f)
#endif
#define QSCALE 0.1803368801111204f   // (1/8) * log2(e)

__device__ __forceinline__ ushort_t f2bf(float f) {
    union { float f; unsigned u; } c; c.f = f;
    unsigned r = c.u + 0x7fffu + ((c.u >> 16) & 1u);   // RNE; inputs finite
    return (ushort_t)(r >> 16);
}

// ---------------------------------------------------------------------------
// fp32 -> bf16 convert, two segments fused (big tensor + weight matrix)
// ---------------------------------------------------------------------------
__global__ __launch_bounds__(256)
void cvt2(const float* __restrict__ s0, ushort_t* __restrict__ d0, int n0,
          const float* __restrict__ s1, ushort_t* __restrict__ d1, int n1)
{
    int i = (blockIdx.x * 256 + threadIdx.x) * 4;
    const float* s; ushort_t* d; int off;
    if (i < n0) { s = s0; d = d0; off = i; }
    else        { s = s1; d = d1; off = i - n0; if (off >= n1) return; }
    f32x4 x = *(const f32x4*)(s + off);
    u16x4 h;
    h[0] = f2bf(x[0]); h[1] = f2bf(x[1]); h[2] = f2bf(x[2]); h[3] = f2bf(x[3]);
    *(u16x4*)(d + off) = h;
}

// ---------------------------------------------------------------------------
// m97-style GEMM: C[M,N] = A[M,K] * W[N,K]^T, all bf16 in, M=8192 N=K=1024.
// 128x128 tile, BK=32, 4 waves (2x2), 64x64 per wave, 4x4 16x16x32 frags.
// global_load_lds width=16 with XOR-swizzled 16B chunks.
// MODE 0: bf16 head-major [b,h,s,dk] (scale applied — Q gets log2e/8)
// MODE 1: bf16 transposed [b,h,dk,s]  (V)
// MODE 2: fp32 row-major [M,N]        (final output)
// ---------------------------------------------------------------------------
template<int MODE>
__global__ __launch_bounds__(256, 2)
void gemm_m97(const ushort_t* __restrict__ A, const ushort_t* __restrict__ W,
              void* __restrict__ out, float scale)
{
    __shared__ ushort_t As[128 * 32];
    __shared__ ushort_t Bs[128 * 32];

    const int tid  = threadIdx.x;
    const int lane = tid & 63;
    const int w    = tid >> 6;
    const int wm   = w >> 1, wn = w & 1;
    const int l15  = lane & 15, l4 = lane >> 4;
    const int m0   = blockIdx.x * 128;
    const int n0   = blockIdx.y * 128;

    f32x4 acc[4][4] = {};

    for (int kk = 0; kk < 1024; kk += 32) {
        #pragma unroll
        for (int i = 0; i < 2; ++i) {
            int c  = i * 256 + w * 64 + lane;          // LDS chunk id 0..511
            int r  = c >> 2;
            int cb = (c & 3) ^ (r & 3);                // swizzled global chunk
            __builtin_amdgcn_global_load_lds(
                GP(A + (size_t)(m0 + r) * 1024 + kk + cb * 8), LP(As + c * 8), 16, 0, 0);
            __builtin_amdgcn_global_load_lds(
                GP(W + (size_t)(n0 + r) * 1024 + kk + cb * 8), LP(Bs + c * 8), 16, 0, 0);
        }
        __syncthreads();

        short8 af[4], bfr[4];
        #pragma unroll
        for (int mi = 0; mi < 4; ++mi) {
            int row = wm * 64 + mi * 16 + l15;
            af[mi] = *(const short8*)(As + (row * 4 + (l4 ^ (row & 3))) * 8);
        }
        #pragma unroll
        for (int ni = 0; ni < 4; ++ni) {
            int row = wn * 64 + ni * 16 + l15;
            bfr[ni] = *(const short8*)(Bs + (row * 4 + (l4 ^ (row & 3))) * 8);
        }
        #pragma unroll
        for (int mi = 0; mi < 4; ++mi)
            #pragma unroll
            for (int ni = 0; ni < 4; ++ni)
                acc[mi][ni] = __builtin_amdgcn_mfma_f32_16x16x32_bf16(
                    af[mi], bfr[ni], acc[mi][ni], 0, 0, 0);
        __syncthreads();
    }

    // ---- epilogue (C/D: col=lane&15, row=(lane>>4)*4+r) ----
    #pragma unroll
    for (int mi = 0; mi < 4; ++mi) {
        int rowb = m0 + wm * 64 + mi * 16 + l4 * 4;
        #pragma unroll
        for (int ni = 0; ni < 4; ++ni) {
            int n = n0 + wn * 64 + ni * 16 + l15;
            if constexpr (MODE == 0) {
                int h = n >> 6, dk = n & 63;
                #pragma unroll
                for (int r = 0; r < 4; ++r) {
                    int m = rowb + r, b = m >> 11, s = m & 2047;
                    ((ushort_t*)out)[(((size_t)(b * 16 + h) * 2048 + s) << 6) + dk] =
                        f2bf(acc[mi][ni][r] * scale);
                }
            } else if constexpr (MODE == 1) {
                int h = n >> 6, dk = n & 63;
                int b = rowb >> 11, s0v = rowb & 2047;   // 4 r's share b (128-aligned tiles)
                u16x4 hh;
                #pragma unroll
                for (int r = 0; r < 4; ++r) hh[r] = f2bf(acc[mi][ni][r]);
                *(u16x4*)((ushort_t*)out + (((size_t)(b * 16 + h) << 6) + dk) * 2048 + s0v) = hh;
            } else {
                #pragma unroll
                for (int r = 0; r < 4; ++r)
                    ((float*)out)[(size_t)(rowb + r) * 1024 + n] = acc[mi][ni][r];
            }
        }
    }
}

// ---------------------------------------------------------------------------
// Flash-style causal attention, S^T orientation, ONLINE-MAX softmax (round-2
// numerics: RNE bf16 P, fp32 pre-quantization row sums, IEEE divide).
// Q,K head-major [b,h,s,dk] bf16 (Q pre-scaled by log2e/8); V transposed
// [b,h,dk,s] bf16. 128 q-rows/block (32/wave), k-tiles of 64.
//   Sc^T = mfma(K-frag, Q-frag): lane holds kcol=l4*4+r, qrow=l15 — a softmax
//   row is 16 in-lane values x 4 lanes -> max/sum = 2 shuffles (xor 16,32).
//   P^T -> per-wave LDS as packed b64 writes, read back as B-frags.
//   O^T = mfma(V^T-frag, P^T-frag). Prefetch staging of tile k+1 under
//   compute. Wave-uniform skip of fully-masked tiles. Ctx out: bf16 [b,s,d].
// ---------------------------------------------------------------------------
__global__ __launch_bounds__(256, 3)
void attn_fwd4(const ushort_t* __restrict__ Qh, const ushort_t* __restrict__ Kh,
               const ushort_t* __restrict__ Vt, ushort_t* __restrict__ Ctx)
{
    __shared__ ushort_t Kl[64 * 64];      // swizzled 16B chunks
    __shared__ ushort_t Vl[64 * 64];      // swizzled 16B chunks
    __shared__ ushort_t Pl[4][32][72];    // per-wave P^T [qrow][kcol], +8 pad

    const int tid  = threadIdx.x;
    const int lane = tid & 63;
    const int w    = tid >> 6;
    const int l15  = lane & 15, l4 = lane >> 4;
    const int idx  = blockIdx.x;
    const int qt   = 15 - (idx >> 6);     // heavy q-tiles first
    const int bh   = idx & 63;
    const int b    = bh >> 4, h = bh & 15;
    const int q0   = qt * 128;
    const ushort_t* Qb = Qh + (size_t)bh * SS * DKK;
    const ushort_t* Kb = Kh + (size_t)bh * SS * DKK;
    const ushort_t* Vb = Vt + (size_t)bh * DKK * SS;

    // Q as B-frags: qrow = q0 + w*32 + qg*16 + l15, dk = ks*32 + l4*8 + j
    short8 qf[2][2];
    #pragma unroll
    for (int qg = 0; qg < 2; ++qg)
        #pragma unroll
        for (int ks = 0; ks < 2; ++ks) {
            int row = q0 + w * 32 + qg * 16 + l15;
            qf[qg][ks] = *(const short8*)(Qb + (size_t)row * 64 + ks * 32 + l4 * 8);
        }

    f32x4 Ot[2][4] = {};     // O^T: [qg][nd], col=l15=qrow, row=l4*4+r=dk
    float m_i[2], l_i[2];    // per-row state (row = qg*16+l15), 4 l4-copies in sync
    m_i[0] = m_i[1] = -__builtin_inff();
    l_i[0] = l_i[1] = 0.f;

    auto stage = [&](int k0) {
        #pragma unroll
        for (int i = 0; i < 2; ++i) {
            int c  = i * 256 + w * 64 + lane;          // 0..511
            int r  = c >> 3;
            int cb = (c & 7) ^ (r & 7);
            __builtin_amdgcn_global_load_lds(
                GP(Kb + (size_t)(k0 + r) * 64 + cb * 8), LP(Kl + c * 8), 16, 0, 0);
            __builtin_amdgcn_global_load_lds(
                GP(Vb + (size_t)r * 2048 + k0 + cb * 8), LP(Vl + c * 8), 16, 0, 0);
        }
    };

    const int nkt = 2 * qt + 2;
    const int wrow0 = q0 + w * 32;        // this wave's first q-row
    stage(0);

    for (int kt = 0; kt < nkt; ++kt) {
        const int k0 = kt * 64;
        const bool act = (k0 <= wrow0 + 31);   // wave-uniform: any unmasked col?
        __syncthreads();                   // staged K/V for tile kt ready

        short8 kf[4][2], vf[2][4];
        if (act) {
            // K as A-frags: kcol = ni*16+l15, dk = ks*32+l4*8+j
            #pragma unroll
            for (int ni = 0; ni < 4; ++ni)
                #pragma unroll
                for (int ks = 0; ks < 2; ++ks) {
                    int r = ni * 16 + l15, cb = ks * 4 + l4;
                    kf[ni][ks] = *(const short8*)(Kl + (r * 8 + (cb ^ (r & 7))) * 8);
                }
            // V^T as A-frags: dk = nd*16+l15, kcol = ks*32+l4*8+j
            #pragma unroll
            for (int ks = 0; ks < 2; ++ks)
                #pragma unroll
                for (int nd = 0; nd < 4; ++nd) {
                    int r = nd * 16 + l15, cb = ks * 4 + l4;
                    vf[ks][nd] = *(const short8*)(Vl + (r * 8 + (cb ^ (r & 7))) * 8);
                }
        }
        __syncthreads();                   // all waves done reading Kl/Vl
        if (kt + 1 < nkt) stage(k0 + 64);  // prefetch next tile under compute
        if (!act) continue;                // barriers already passed (uniform)

        // ---- Sc^T = K * Q^T : [kcol][qrow] ----
        f32x4 sc[2][4] = {};               // [qg][ni]: kcol=ni*16+l4*4+r, qrow=qg*16+l15
        #pragma unroll
        for (int qg = 0; qg < 2; ++qg)
            #pragma unroll
            for (int ni = 0; ni < 4; ++ni)
                #pragma unroll
                for (int ks = 0; ks < 2; ++ks)
                    sc[qg][ni] = __builtin_amdgcn_mfma_f32_16x16x32_bf16(
                        kf[ni][ks], qf[qg][ks], sc[qg][ni], 0, 0, 0);

        // ---- causal mask (only near-diagonal tiles) ----
        if (k0 + 63 > wrow0) {
            #pragma unroll
            for (int qg = 0; qg < 2; ++qg) {
                int qrow = wrow0 + qg * 16 + l15;
                #pragma unroll
                for (int ni = 0; ni < 4; ++ni)
                    #pragma unroll
                    for (int r = 0; r < 4; ++r) {
                        int kcol = k0 + ni * 16 + l4 * 4 + r;
                        if (kcol > qrow) sc[qg][ni][r] = -1.0e30f;
                    }
            }
        }

        // ---- online softmax: row = (qg,l15); 16 in-lane + 2 shuffles ----
        #pragma unroll
        for (int qg = 0; qg < 2; ++qg) {
            float mx = sc[qg][0][0];
            #pragma unroll
            for (int ni = 0; ni < 4; ++ni)
                #pragma unroll
                for (int r = 0; r < 4; ++r) mx = fmaxf(mx, sc[qg][ni][r]);
            mx = fmaxf(mx, __shfl_xor(mx, 16, 64));
            mx = fmaxf(mx, __shfl_xor(mx, 32, 64));
            float mnew  = fmaxf(m_i[qg], mx);
            float alpha = EXP2(m_i[qg] - mnew);   // -inf - finite -> 0, no NaN
            float rs = 0.f;
            #pragma unroll
            for (int ni = 0; ni < 4; ++ni)
                #pragma unroll
                for (int r = 0; r < 4; ++r) {
                    float p = EXP2(sc[qg][ni][r] - mnew);
                    sc[qg][ni][r] = p;
                    rs += p;
                }
            rs += __shfl_xor(rs, 16, 64);
            rs += __shfl_xor(rs, 32, 64);
            l_i[qg] = l_i[qg] * alpha + rs;       // fp32 pre-quantization sum
            m_i[qg] = mnew;
            #pragma unroll
            for (int nd = 0; nd < 4; ++nd)
                #pragma unroll
                for (int r = 0; r < 4; ++r) Ot[qg][nd][r] *= alpha;
        }

        // ---- P^T -> per-wave LDS, RNE bf16, packed b64 writes ----
        #pragma unroll
        for (int qg = 0; qg < 2; ++qg) {
            int qr = qg * 16 + l15;
            #pragma unroll
            for (int ni = 0; ni < 4; ++ni) {
                u16x4 hh;
                #pragma unroll
                for (int r = 0; r < 4; ++r) hh[r] = f2bf(sc[qg][ni][r]);
                *(u16x4*)(&Pl[w][qr][ni * 16 + l4 * 4]) = hh;
            }
        }

        // ---- read back as B-frags: P^T[k=kcol][n=qrow] ----
        short8 pT[2][2];
        #pragma unroll
        for (int qg = 0; qg < 2; ++qg)
            #pragma unroll
            for (int ks = 0; ks < 2; ++ks)
                pT[qg][ks] = *(const short8*)(&Pl[w][qg * 16 + l15][ks * 32 + l4 * 8]);

        // ---- O^T += V^T * P^T ----
        #pragma unroll
        for (int qg = 0; qg < 2; ++qg)
            #pragma unroll
            for (int nd = 0; nd < 4; ++nd)
                #pragma unroll
                for (int ks = 0; ks < 2; ++ks)
                    Ot[qg][nd] = __builtin_amdgcn_mfma_f32_16x16x32_bf16(
                        vf[ks][nd], pT[qg][ks], Ot[qg][nd], 0, 0, 0);
    }

    // ---- epilogue: Ctx[b, qrow, h*64+dk] = O^T / l, packed u16x4 ----
    #pragma unroll
    for (int qg = 0; qg < 2; ++qg) {
        float inv = 1.0f / l_i[qg];           // IEEE divide (round-2 numerics)
        int qrow = q0 + w * 32 + qg * 16 + l15;
        ushort_t* dst = Ctx + ((size_t)b * 2048 + qrow) * 1024 + h * 64;
        #pragma unroll
        for (int nd = 0; nd < 4; ++nd) {
            u16x4 hh;
            #pragma unroll
            for (int r = 0; r < 4; ++r) hh[r] = f2bf(Ot[qg][nd][r] * inv);
            *(u16x4*)(dst + nd * 16 + l4 * 4) = hh;
        }
    }
}

// ---------------------------------------------------------------------------
extern "C" void kernel_launch(void* const* d_in, const int* in_sizes, int n_in,
                              void* d_out, int out_size, void* d_ws, size_t ws_size,
                              hipStream_t stream)
{
    const float* q  = (const float*)d_in[0];
    const float* k  = (const float*)d_in[1];
    const float* v  = (const float*)d_in[2];
    const float* Wq = (const float*)d_in[3];
    const float* Wk = (const float*)d_in[4];
    const float* Wv = (const float*)d_in[5];
    const float* Wo = (const float*)d_in[6];
    float* out = (float*)d_out;

    // workspace: 4 x 16.78 MB bf16 buffers = 67.1 MB
    ushort_t* B0 = (ushort_t*)d_ws;            // cvt scratch, later Ctx
    ushort_t* B1 = B0 + (size_t)QKV_N;         // Qh, later Wo-bf16 scratch
    ushort_t* B2 = B1 + (size_t)QKV_N;         // Kh
    ushort_t* B3 = B2 + (size_t)QKV_N;         // Vt [b,h,dk,s]
    ushort_t* wbE = (ushort_t*)d_out;          // 2 MB W scratch inside out buf
                                               // (final GEMM overwrites all)
    dim3 gg(MTOT / 128, DD / 128);             // (64, 8)
    const int cvtg = (QKV_N + W_N) / 1024;     // 9216

    cvt2<<<cvtg, 256, 0, stream>>>(q, B0, QKV_N, Wq, wbE, W_N);
    gemm_m97<0><<<gg, 256, 0, stream>>>(B0, wbE, B1, QSCALE);   // Q, exp2-domain scale

    cvt2<<<cvtg, 256, 0, stream>>>(k, B0, QKV_N, Wk, wbE, W_N);
    gemm_m97<0><<<gg, 256, 0, stream>>>(B0, wbE, B2, 1.0f);     // K

    cvt2<<<cvtg, 256, 0, stream>>>(v, B0, QKV_N, Wv, wbE, W_N);
    gemm_m97<1><<<gg, 256, 0, stream>>>(B0, wbE, B3, 1.0f);     // V transposed

    attn_fwd4<<<1024, 256, 0, stream>>>(B1, B2, B3, B0);        // Ctx -> B0

    cvt2<<<W_N / 1024, 256, 0, stream>>>(Wo, B1, W_N, Wo, B1, 0);
    gemm_m97<2><<<gg, 256, 0, stream>>>(B0, B1, out, 1.0f);     // final fp32
}

// Round 5
// 334.807 us; speedup vs baseline: 1.3210x; 1.3210x over previous
//
#include <hip/hip_runtime.h>

// Problem constants: B=4, S=2048, D=1024, H=16, DK=64
#define BB 4
#define SS 2048
#define DD 1024
#define HH 16
#define DKK 64
#define MTOT (BB * SS)          // 8192
#define QKV_N (MTOT * DD)       // 8388608
#define W_N (DD * DD)           // 1048576

typedef __attribute__((ext_vector_type(8))) short short8;     // 8 bf16 (MFMA A/B frag)
typedef __attribute__((ext_vector_type(4))) float f32x4;      // MFMA C/D frag
typedef __attribute__((ext_vector_type(4))) unsigned short u16x4;
typedef unsigned short ushort_t;

#define GP(p) ((__attribute__((address_space(1))) void*)(p))
#define LP(p) ((__attribute__((address_space(3))) void*)(p))

// exp2-domain softmax: Q pre-scaled by log2(e)/8 so p = 2^(s-m) via v_exp_f32
#if __has_builtin(__builtin_amdgcn_exp2f)
#define EXP2(x) __builtin_amdgcn_exp2f(x)
#else
#define EXP2(x) __expf((x) * 0.6931471805599453f)
#endif
#define QSCALE 0.1803368801111204f   // (1/8) * log2(e)

__device__ __forceinline__ ushort_t f2bf(float f) {
    union { float f; unsigned u; } c; c.f = f;
    unsigned r = c.u + 0x7fffu + ((c.u >> 16) & 1u);   // RNE; inputs finite
    return (ushort_t)(r >> 16);
}

// ---------------------------------------------------------------------------
// fp32 -> bf16 convert, two segments fused (big tensor + weight matrix)
// ---------------------------------------------------------------------------
__global__ __launch_bounds__(256)
void cvt2(const float* __restrict__ s0, ushort_t* __restrict__ d0, int n0,
          const float* __restrict__ s1, ushort_t* __restrict__ d1, int n1)
{
    int i = (blockIdx.x * 256 + threadIdx.x) * 4;
    const float* s; ushort_t* d; int off;
    if (i < n0) { s = s0; d = d0; off = i; }
    else        { s = s1; d = d1; off = i - n0; if (off >= n1) return; }
    f32x4 x = *(const f32x4*)(s + off);
    u16x4 h;
    h[0] = f2bf(x[0]); h[1] = f2bf(x[1]); h[2] = f2bf(x[2]); h[3] = f2bf(x[3]);
    *(u16x4*)(d + off) = h;
}

// ---------------------------------------------------------------------------
// m97-style GEMM: C[M,N] = A[M,K] * W[N,K]^T, all bf16 in, M=8192 N=K=1024.
// 128x128 tile, BK=32, 4 waves (2x2), 64x64 per wave, 4x4 16x16x32 frags.
// global_load_lds width=16 with XOR-swizzled 16B chunks.
// MODE 0: bf16 head-major [b,h,s,dk] (scale applied — Q gets log2e/8)
// MODE 1: bf16 transposed [b,h,dk,s]  (V)
// MODE 2: fp32 row-major [M,N]        (final output)
// ---------------------------------------------------------------------------
template<int MODE>
__global__ __launch_bounds__(256, 2)
void gemm_m97(const ushort_t* __restrict__ A, const ushort_t* __restrict__ W,
              void* __restrict__ out, float scale)
{
    __shared__ ushort_t As[128 * 32];
    __shared__ ushort_t Bs[128 * 32];

    const int tid  = threadIdx.x;
    const int lane = tid & 63;
    const int w    = tid >> 6;
    const int wm   = w >> 1, wn = w & 1;
    const int l15  = lane & 15, l4 = lane >> 4;
    const int m0   = blockIdx.x * 128;
    const int n0   = blockIdx.y * 128;

    f32x4 acc[4][4] = {};

    for (int kk = 0; kk < 1024; kk += 32) {
        #pragma unroll
        for (int i = 0; i < 2; ++i) {
            int c  = i * 256 + w * 64 + lane;          // LDS chunk id 0..511
            int r  = c >> 2;
            int cb = (c & 3) ^ (r & 3);                // swizzled global chunk
            __builtin_amdgcn_global_load_lds(
                GP(A + (size_t)(m0 + r) * 1024 + kk + cb * 8), LP(As + c * 8), 16, 0, 0);
            __builtin_amdgcn_global_load_lds(
                GP(W + (size_t)(n0 + r) * 1024 + kk + cb * 8), LP(Bs + c * 8), 16, 0, 0);
        }
        __syncthreads();

        short8 af[4], bfr[4];
        #pragma unroll
        for (int mi = 0; mi < 4; ++mi) {
            int row = wm * 64 + mi * 16 + l15;
            af[mi] = *(const short8*)(As + (row * 4 + (l4 ^ (row & 3))) * 8);
        }
        #pragma unroll
        for (int ni = 0; ni < 4; ++ni) {
            int row = wn * 64 + ni * 16 + l15;
            bfr[ni] = *(const short8*)(Bs + (row * 4 + (l4 ^ (row & 3))) * 8);
        }
        #pragma unroll
        for (int mi = 0; mi < 4; ++mi)
            #pragma unroll
            for (int ni = 0; ni < 4; ++ni)
                acc[mi][ni] = __builtin_amdgcn_mfma_f32_16x16x32_bf16(
                    af[mi], bfr[ni], acc[mi][ni], 0, 0, 0);
        __syncthreads();
    }

    // ---- epilogue (C/D: col=lane&15, row=(lane>>4)*4+r) ----
    #pragma unroll
    for (int mi = 0; mi < 4; ++mi) {
        int rowb = m0 + wm * 64 + mi * 16 + l4 * 4;
        #pragma unroll
        for (int ni = 0; ni < 4; ++ni) {
            int n = n0 + wn * 64 + ni * 16 + l15;
            if constexpr (MODE == 0) {
                int h = n >> 6, dk = n & 63;
                #pragma unroll
                for (int r = 0; r < 4; ++r) {
                    int m = rowb + r, b = m >> 11, s = m & 2047;
                    ((ushort_t*)out)[(((size_t)(b * 16 + h) * 2048 + s) << 6) + dk] =
                        f2bf(acc[mi][ni][r] * scale);
                }
            } else if constexpr (MODE == 1) {
                int h = n >> 6, dk = n & 63;
                int b = rowb >> 11, s0v = rowb & 2047;   // 4 r's share b (128-aligned tiles)
                u16x4 hh;
                #pragma unroll
                for (int r = 0; r < 4; ++r) hh[r] = f2bf(acc[mi][ni][r]);
                *(u16x4*)((ushort_t*)out + (((size_t)(b * 16 + h) << 6) + dk) * 2048 + s0v) = hh;
            } else {
                #pragma unroll
                for (int r = 0; r < 4; ++r)
                    ((float*)out)[(size_t)(rowb + r) * 1024 + n] = acc[mi][ni][r];
            }
        }
    }
}

// ---------------------------------------------------------------------------
// Flash-style causal attention, S^T orientation, online-max softmax (round-2
// numerics: RNE bf16 P, fp32 pre-quantization row sums, IEEE divide).
// Q,K head-major [b,h,s,dk] bf16 (Q pre-scaled by log2e/8); V transposed
// [b,h,dk,s] bf16. 128 q-rows/block (32/wave), k-tiles of 64.
// DOUBLE-BUFFERED K/V LDS: one barrier per tile; prefetch of tile k+1 issued
// right after the barrier, drains at the NEXT barrier (a full tile of compute
// hides it). Fragments loaded just-in-time (kf before QK, vf before PV) to
// keep register live ranges short — R4's hoisted/conditional frags spilled
// (WRITE_SIZE 16->201 MB). No act-skip. Ctx out: bf16 [b,s,d].
// ---------------------------------------------------------------------------
__global__ __launch_bounds__(256, 2)
void attn_fwd5(const ushort_t* __restrict__ Qh, const ushort_t* __restrict__ Kh,
               const ushort_t* __restrict__ Vt, ushort_t* __restrict__ Ctx)
{
    __shared__ ushort_t Kl[2][64 * 64];   // swizzled 16B chunks, double-buffered
    __shared__ ushort_t Vl[2][64 * 64];
    __shared__ ushort_t Pl[4][32][72];    // per-wave P^T [qrow][kcol], +8 pad

    const int tid  = threadIdx.x;
    const int lane = tid & 63;
    const int w    = tid >> 6;
    const int l15  = lane & 15, l4 = lane >> 4;
    const int idx  = blockIdx.x;
    const int qt   = 15 - (idx >> 6);     // heavy q-tiles first
    const int bh   = idx & 63;
    const int b    = bh >> 4, h = bh & 15;
    const int q0   = qt * 128;
    const ushort_t* Qb = Qh + (size_t)bh * SS * DKK;
    const ushort_t* Kb = Kh + (size_t)bh * SS * DKK;
    const ushort_t* Vb = Vt + (size_t)bh * DKK * SS;

    // Q as B-frags: qrow = q0 + w*32 + qg*16 + l15, dk = ks*32 + l4*8 + j
    short8 qf[2][2];
    #pragma unroll
    for (int qg = 0; qg < 2; ++qg)
        #pragma unroll
        for (int ks = 0; ks < 2; ++ks) {
            int row = q0 + w * 32 + qg * 16 + l15;
            qf[qg][ks] = *(const short8*)(Qb + (size_t)row * 64 + ks * 32 + l4 * 8);
        }

    f32x4 Ot[2][4] = {};     // O^T: [qg][nd], col=l15=qrow, row=l4*4+r=dk
    float m_i[2], l_i[2];    // per-row state (row = qg*16+l15), 4 l4-copies in sync
    m_i[0] = m_i[1] = -__builtin_inff();
    l_i[0] = l_i[1] = 0.f;

    auto stage = [&](int k0, ushort_t* Kd, ushort_t* Vd) {
        #pragma unroll
        for (int i = 0; i < 2; ++i) {
            int c  = i * 256 + tid;                    // 0..511
            int r  = c >> 3;
            int cb = (c & 7) ^ (r & 7);
            __builtin_amdgcn_global_load_lds(
                GP(Kb + (size_t)(k0 + r) * 64 + cb * 8), LP(Kd + c * 8), 16, 0, 0);
            __builtin_amdgcn_global_load_lds(
                GP(Vb + (size_t)r * 2048 + k0 + cb * 8), LP(Vd + c * 8), 16, 0, 0);
        }
    };

    const int nkt = 2 * qt + 2;
    const int wrow0 = q0 + w * 32;        // this wave's first q-row
    stage(0, Kl[0], Vl[0]);

    for (int kt = 0; kt < nkt; ++kt) {
        const int k0 = kt * 64;
        __syncthreads();                   // buf[kt&1] staged; prev prefetch drained
        const ushort_t* Kc = Kl[kt & 1];
        const ushort_t* Vc = Vl[kt & 1];
        if (kt + 1 < nkt)                  // prefetch under this tile's compute
            stage(k0 + 64, Kl[(kt + 1) & 1], Vl[(kt + 1) & 1]);

        // ---- Sc^T = K * Q^T : [kcol][qrow]; kf loaded just-in-time ----
        f32x4 sc[2][4] = {};               // [qg][ni]: kcol=ni*16+l4*4+r, qrow=qg*16+l15
        #pragma unroll
        for (int ni = 0; ni < 4; ++ni) {
            short8 kf0, kf1;
            {
                int r = ni * 16 + l15;
                kf0 = *(const short8*)(Kc + (r * 8 + ((0 + l4) ^ (r & 7))) * 8);
                kf1 = *(const short8*)(Kc + (r * 8 + ((4 + l4) ^ (r & 7))) * 8);
            }
            #pragma unroll
            for (int qg = 0; qg < 2; ++qg) {
                sc[qg][ni] = __builtin_amdgcn_mfma_f32_16x16x32_bf16(
                    kf0, qf[qg][0], sc[qg][ni], 0, 0, 0);
                sc[qg][ni] = __builtin_amdgcn_mfma_f32_16x16x32_bf16(
                    kf1, qf[qg][1], sc[qg][ni], 0, 0, 0);
            }
        }

        // ---- causal mask (only near-diagonal tiles) ----
        if (k0 + 63 > wrow0) {
            #pragma unroll
            for (int qg = 0; qg < 2; ++qg) {
                int qrow = wrow0 + qg * 16 + l15;
                #pragma unroll
                for (int ni = 0; ni < 4; ++ni)
                    #pragma unroll
                    for (int r = 0; r < 4; ++r) {
                        int kcol = k0 + ni * 16 + l4 * 4 + r;
                        if (kcol > qrow) sc[qg][ni][r] = -1.0e30f;
                    }
            }
        }

        // ---- online softmax: row = (qg,l15); 16 in-lane + 2 shuffles ----
        #pragma unroll
        for (int qg = 0; qg < 2; ++qg) {
            float mx = sc[qg][0][0];
            #pragma unroll
            for (int ni = 0; ni < 4; ++ni)
                #pragma unroll
                for (int r = 0; r < 4; ++r) mx = fmaxf(mx, sc[qg][ni][r]);
            mx = fmaxf(mx, __shfl_xor(mx, 16, 64));
            mx = fmaxf(mx, __shfl_xor(mx, 32, 64));
            float mnew  = fmaxf(m_i[qg], mx);
            float alpha = EXP2(m_i[qg] - mnew);   // -inf - finite -> 0, no NaN
            float rs = 0.f;
            #pragma unroll
            for (int ni = 0; ni < 4; ++ni)
                #pragma unroll
                for (int r = 0; r < 4; ++r) {
                    float p = EXP2(sc[qg][ni][r] - mnew);
                    sc[qg][ni][r] = p;
                    rs += p;
                }
            rs += __shfl_xor(rs, 16, 64);
            rs += __shfl_xor(rs, 32, 64);
            l_i[qg] = l_i[qg] * alpha + rs;       // fp32 pre-quantization sum
            m_i[qg] = mnew;
            #pragma unroll
            for (int nd = 0; nd < 4; ++nd)
                #pragma unroll
                for (int r = 0; r < 4; ++r) Ot[qg][nd][r] *= alpha;
        }

        // ---- P^T -> per-wave LDS, RNE bf16, packed b64 writes ----
        #pragma unroll
        for (int qg = 0; qg < 2; ++qg) {
            int qr = qg * 16 + l15;
            #pragma unroll
            for (int ni = 0; ni < 4; ++ni) {
                u16x4 hh;
                #pragma unroll
                for (int r = 0; r < 4; ++r) hh[r] = f2bf(sc[qg][ni][r]);
                *(u16x4*)(&Pl[w][qr][ni * 16 + l4 * 4]) = hh;
            }
        }

        // ---- read back as B-frags: P^T[k=kcol][n=qrow] ----
        short8 pT[2][2];
        #pragma unroll
        for (int qg = 0; qg < 2; ++qg)
            #pragma unroll
            for (int ks = 0; ks < 2; ++ks)
                pT[qg][ks] = *(const short8*)(&Pl[w][qg * 16 + l15][ks * 32 + l4 * 8]);

        // ---- O^T += V^T * P^T ; vf loaded just-in-time ----
        #pragma unroll
        for (int nd = 0; nd < 4; ++nd) {
            short8 vf0, vf1;
            {
                int r = nd * 16 + l15;
                vf0 = *(const short8*)(Vc + (r * 8 + ((0 + l4) ^ (r & 7))) * 8);
                vf1 = *(const short8*)(Vc + (r * 8 + ((4 + l4) ^ (r & 7))) * 8);
            }
            #pragma unroll
            for (int qg = 0; qg < 2; ++qg) {
                Ot[qg][nd] = __builtin_amdgcn_mfma_f32_16x16x32_bf16(
                    vf0, pT[qg][0], Ot[qg][nd], 0, 0, 0);
                Ot[qg][nd] = __builtin_amdgcn_mfma_f32_16x16x32_bf16(
                    vf1, pT[qg][1], Ot[qg][nd], 0, 0, 0);
            }
        }
    }

    // ---- epilogue: Ctx[b, qrow, h*64+dk] = O^T / l, packed u16x4 ----
    #pragma unroll
    for (int qg = 0; qg < 2; ++qg) {
        float inv = 1.0f / l_i[qg];           // IEEE divide (round-2 numerics)
        int qrow = q0 + w * 32 + qg * 16 + l15;
        ushort_t* dst = Ctx + ((size_t)b * 2048 + qrow) * 1024 + h * 64;
        #pragma unroll
        for (int nd = 0; nd < 4; ++nd) {
            u16x4 hh;
            #pragma unroll
            for (int r = 0; r < 4; ++r) hh[r] = f2bf(Ot[qg][nd][r] * inv);
            *(u16x4*)(dst + nd * 16 + l4 * 4) = hh;
        }
    }
}

// ---------------------------------------------------------------------------
extern "C" void kernel_launch(void* const* d_in, const int* in_sizes, int n_in,
                              void* d_out, int out_size, void* d_ws, size_t ws_size,
                              hipStream_t stream)
{
    const float* q  = (const float*)d_in[0];
    const float* k  = (const float*)d_in[1];
    const float* v  = (const float*)d_in[2];
    const float* Wq = (const float*)d_in[3];
    const float* Wk = (const float*)d_in[4];
    const float* Wv = (const float*)d_in[5];
    const float* Wo = (const float*)d_in[6];
    float* out = (float*)d_out;

    // workspace: 4 x 16.78 MB bf16 buffers = 67.1 MB
    ushort_t* B0 = (ushort_t*)d_ws;            // cvt scratch, later Ctx
    ushort_t* B1 = B0 + (size_t)QKV_N;         // Qh, later Wo-bf16 scratch
    ushort_t* B2 = B1 + (size_t)QKV_N;         // Kh
    ushort_t* B3 = B2 + (size_t)QKV_N;         // Vt [b,h,dk,s]
    ushort_t* wbE = (ushort_t*)d_out;          // 2 MB W scratch inside out buf
                                               // (final GEMM overwrites all)
    dim3 gg(MTOT / 128, DD / 128);             // (64, 8)
    const int cvtg = (QKV_N + W_N) / 1024;     // 9216

    cvt2<<<cvtg, 256, 0, stream>>>(q, B0, QKV_N, Wq, wbE, W_N);
    gemm_m97<0><<<gg, 256, 0, stream>>>(B0, wbE, B1, QSCALE);   // Q, exp2-domain scale

    cvt2<<<cvtg, 256, 0, stream>>>(k, B0, QKV_N, Wk, wbE, W_N);
    gemm_m97<0><<<gg, 256, 0, stream>>>(B0, wbE, B2, 1.0f);     // K

    cvt2<<<cvtg, 256, 0, stream>>>(v, B0, QKV_N, Wv, wbE, W_N);
    gemm_m97<1><<<gg, 256, 0, stream>>>(B0, wbE, B3, 1.0f);     // V transposed

    attn_fwd5<<<1024, 256, 0, stream>>>(B1, B2, B3, B0);        // Ctx -> B0

    cvt2<<<W_N / 1024, 256, 0, stream>>>(Wo, B1, W_N, Wo, B1, 0);
    gemm_m97<2><<<gg, 256, 0, stream>>>(B0, B1, out, 1.0f);     // final fp32
}